// Round 7
// baseline (755.953 us; speedup 1.0000x reference)
//
#include <hip/hip_runtime.h>

// GraphSAGE 2-layer, N=50000, d=128->32->32, E=800000, fp32.
//
// R12: INSTRUMENTATION ROUND. R9-R11 were all null; per-kernel times are
// invisible (harness 44us fills flood rocprof top-5; ours all <44us). This
// round = R11 exactly, but each kernel repeats its body REP=6 times
// (runtime arg => no unroll; k_front build uses 6 independent gcnt/ebuf
// copies so all reps do identical work; fagg kernels idempotent, re-run
// whole body; final rep writes canonical outputs => correctness unchanged).
// Each kernel's duration x6 -> surfaces in top-5 -> unit time = shown/6.
// Decision tree for R13 is pre-committed in the session journal.
// ws: zl|zr|z2l|z2r [N*32] | ebuf[REP*NB*CAPE] | gcnt[REP*NB*32]  (~50MB)

#define N_NODES 50000
#define NB 782     // buckets = ceil(N/64)
#define BKS 64     // nodes per bucket
#define GB 256     // build blocks
#define CAPE 1280  // per-bucket capacity (mean 1023, sd 32; R8-verified)
#define TILE 3200  // build LDS staging tile (chunk=3128 fits in one)
#define REP 6      // instrumentation repeat factor

// ---- k_front: build (blocks < GB) + L1 projection (blocks >= GB) ---------
__global__ __launch_bounds__(256) void k_front(
    const float* __restrict__ in, const float* __restrict__ Wl,
    const float* __restrict__ Wr, float* __restrict__ zl,
    float* __restrict__ zr, int N, int K, const int* __restrict__ src,
    const int* __restrict__ dst, int* __restrict__ gcnt,
    int* __restrict__ ebuf, int E, int rep_n) {
  __shared__ __align__(16) union {
    struct { float xs[64 * 68]; float ws[64 * 64]; } p;          // 33.8 KB
    struct { unsigned pe[TILE]; int hist[NB]; int cur[NB]; } b;  // 19.1 KB
  } sm;
  const int t = threadIdx.x;

  if (blockIdx.x < GB) {
    // ---------------- build role ----------------
    const int chunk = (((E + GB - 1) / GB) + 3) & ~3;  // 3128: 16B-aligned e0
    const int e0 = blockIdx.x * chunk;
    int e1 = e0 + chunk;
    if (e1 > E) e1 = E;
    for (int rep = 0; rep < rep_n; ++rep) {
      int* gc = gcnt + (size_t)rep * NB * 32;
      int* eb = ebuf + (size_t)rep * NB * CAPE;
      for (int ts = e0; ts < e1; ts += TILE) {
        int te = ts + TILE;
        if (te > e1) te = e1;
        const int n = te - ts;
        if (n <= 0) break;
        for (int i = t; i < NB; i += 256) sm.b.hist[i] = 0;
        __syncthreads();
        {
          const int n4 = n >> 2;
          const int4* s4 = (const int4*)(src + ts);
          const int4* d4 = (const int4*)(dst + ts);
          for (int i = t; i < n4; i += 256) {
            int4 sv = s4[i];
            int4 dv = d4[i];
            int4 pk;
            pk.x = (sv.x << 16) | dv.x;
            pk.y = (sv.y << 16) | dv.y;
            pk.z = (sv.z << 16) | dv.z;
            pk.w = (sv.w << 16) | dv.w;
            *(int4*)(sm.b.pe + 4 * i) = pk;
            atomicAdd(&sm.b.hist[dv.x >> 6], 1);
            atomicAdd(&sm.b.hist[dv.y >> 6], 1);
            atomicAdd(&sm.b.hist[dv.z >> 6], 1);
            atomicAdd(&sm.b.hist[dv.w >> 6], 1);
          }
          for (int i = (n4 << 2) + t; i < n; i += 256) {
            unsigned s = (unsigned)src[ts + i];
            unsigned d = (unsigned)dst[ts + i];
            sm.b.pe[i] = (s << 16) | d;
            atomicAdd(&sm.b.hist[d >> 6], 1);
          }
        }
        __syncthreads();
        for (int c = t; c < NB; c += 256) {
          int h = sm.b.hist[c];
          sm.b.cur[c] = h ? atomicAdd(&gc[c * 32], h) : 0;
        }
        __syncthreads();
        for (int i = t; i < n; i += 256) {
          unsigned pe = sm.b.pe[i];
          int d = (int)(pe & 0xFFFFu);
          int s = (int)(pe >> 16);
          int c = d >> 6;
          int p = atomicAdd(&sm.b.cur[c], 1);
          if (p < CAPE) eb[(size_t)c * CAPE + p] = (s << 6) | (d & 63);
        }
        __syncthreads();
      }
    }
    return;
  }

  // ------- projection role: zl[n][0:32)=in@Wl, zr[n][0:32)=in@Wr ----------
  const int n0 = (blockIdx.x - GB) * 64;
  const int nvalid = (N - n0) < 64 ? (N - n0) : 64;
  const int tx = t & 15, ty = t >> 4;
  const int c0 = tx * 4;
  const int nl = ty * 4;

  for (int rep = 0; rep < rep_n; ++rep) {
    float acc[4][4];
#pragma unroll
    for (int i = 0; i < 4; i++)
#pragma unroll
      for (int j = 0; j < 4; j++) acc[i][j] = 0.f;

    for (int kc = 0; kc < K; kc += 64) {
      const int KC = (K - kc) < 64 ? (K - kc) : 64;
      for (int i = t; i < KC * 32; i += 256) {
        int k = i >> 5, c = i & 31;
        sm.p.ws[k * 64 + c] = Wl[(size_t)(kc + k) * 32 + c];
        sm.p.ws[k * 64 + 32 + c] = Wr[(size_t)(kc + k) * 32 + c];
      }
      {
        const int kq = KC >> 2;
        const int sh = (KC == 64) ? 4 : 3;
        const int lim = nvalid * kq;
        for (int i = t; i < lim; i += 256) {
          int n = i >> sh, q = i & (kq - 1);
          float4 v = *(const float4*)(in + (size_t)(n0 + n) * K + kc + q * 4);
          *(float4*)(sm.p.xs + n * 68 + q * 4) = v;
        }
      }
      __syncthreads();

      const float* x0 = sm.p.xs + (nl + 0) * 68;
      const float* x1 = sm.p.xs + (nl + 1) * 68;
      const float* x2 = sm.p.xs + (nl + 2) * 68;
      const float* x3 = sm.p.xs + (nl + 3) * 68;
      for (int k = 0; k < KC; k += 4) {
        float4 xa = *(const float4*)(x0 + k);
        float4 xb = *(const float4*)(x1 + k);
        float4 xc = *(const float4*)(x2 + k);
        float4 xd = *(const float4*)(x3 + k);
#pragma unroll
        for (int kk = 0; kk < 4; kk++) {
          float4 w = *(const float4*)(sm.p.ws + (k + kk) * 64 + c0);
          float va = ((const float*)&xa)[kk];
          float vb = ((const float*)&xb)[kk];
          float vc = ((const float*)&xc)[kk];
          float vd = ((const float*)&xd)[kk];
          acc[0][0] += va * w.x; acc[0][1] += va * w.y;
          acc[0][2] += va * w.z; acc[0][3] += va * w.w;
          acc[1][0] += vb * w.x; acc[1][1] += vb * w.y;
          acc[1][2] += vb * w.z; acc[1][3] += vb * w.w;
          acc[2][0] += vc * w.x; acc[2][1] += vc * w.y;
          acc[2][2] += vc * w.z; acc[2][3] += vc * w.w;
          acc[3][0] += vd * w.x; acc[3][1] += vd * w.y;
          acc[3][2] += vd * w.z; acc[3][3] += vd * w.w;
        }
      }
      __syncthreads();
    }
#pragma unroll
    for (int i = 0; i < 4; i++) {
      int node = n0 + nl + i;
      if (node < N) {
        float4 v = make_float4(acc[i][0], acc[i][1], acc[i][2], acc[i][3]);
        if (c0 < 32)
          *(float4*)(zl + (size_t)node * 32 + c0) = v;
        else
          *(float4*)(zr + (size_t)node * 32 + (c0 - 32)) = v;
      }
    }
    __syncthreads();
  }
}

// ---- shared phase 0: load bucket edges + LDS counting sort (int-only) ----
#define SORT_PHASE(EBUF, NE)                                             \
  {                                                                      \
    const int ne4 = (NE) >> 2;                                           \
    const int4* eb4 = (const int4*)((EBUF) + base);                      \
    for (int i = t; i < ne4; i += 512) {                                 \
      int4 v = eb4[i];                                                   \
      *(int4*)(lds_e + 4 * i) = v;                                       \
    }                                                                    \
    for (int i = (ne4 << 2) + t; i < (NE); i += 512)                     \
      lds_e[i] = (EBUF)[base + i];                                       \
  }                                                                      \
  if (t < BKS) deg[t] = 0;                                               \
  __syncthreads();                                                       \
  for (int i = t; i < (NE); i += 512) atomicAdd(&deg[lds_e[i] & 63], 1); \
  __syncthreads();                                                       \
  if (t < 64) {                                                          \
    int d = deg[t];                                                      \
    int x = d;                                                           \
    _Pragma("unroll") for (int o = 1; o < 64; o <<= 1) {                 \
      int y = __shfl_up(x, o, 64);                                       \
      if (t >= o) x += y;                                                \
    }                                                                    \
    off[t] = x - d;                                                      \
    cur[t] = x - d;                                                      \
  }                                                                      \
  __syncthreads();                                                       \
  for (int i = t; i < (NE); i += 512) {                                  \
    int v = lds_e[i];                                                    \
    int p = atomicAdd(&cur[v & 63], 1);                                  \
    lds_s[p] = v >> 6;                                                   \
  }                                                                      \
  __syncthreads();

// ---- fused L1: sort + wide gather + relu + W2 proj -> z2l/z2r ------------
__global__ __launch_bounds__(512) void k_fagg1(
    const float* __restrict__ zl, const float* __restrict__ zr,
    const int* __restrict__ ebuf, const int* __restrict__ gcnt,
    const float* __restrict__ b1, const float* __restrict__ W2l,
    const float* __restrict__ W2r, float* __restrict__ z2l,
    float* __restrict__ z2r, int N, int rep_n) {
  __shared__ __align__(16) int lds_e[CAPE];
  __shared__ int lds_s[CAPE];
  __shared__ int deg[BKS];
  __shared__ int cur[BKS];
  __shared__ int off[BKS];
  __shared__ float w2p[32 * 64];  // [jj][0:32]=W2l[jj], [32:64]=W2r[jj]
  __shared__ __align__(16) float bsh[32];
  __shared__ __align__(16) float hbuf[BKS * 36];  // h, stride 36 (16B-align)
  const int t = threadIdx.x;
  const int k = blockIdx.x;
  int ne = gcnt[k * 32];
  if (ne > CAPE) ne = CAPE;
  const size_t base = (size_t)k * CAPE;

  for (int rep = 0; rep < rep_n; ++rep) {
    for (int i = t; i < 2048; i += 512) {
      int jj = i >> 6, c = i & 63;
      w2p[i] = (c < 32) ? W2l[jj * 32 + c] : W2r[jj * 32 + (c - 32)];
    }
    if (t < 32) bsh[t] = b1[t];

    SORT_PHASE(ebuf, ne)

    const float4* zl4 = (const float4*)zl;  // row = 8 float4
    const int w = t >> 6, l = t & 63;
    const int es = l >> 3, fi = l & 7;
    const int n0 = k << 6;
    const int w8 = w * 8;
#pragma unroll
    for (int p = 0; p < 8; p += 2) {
      const int nA = w8 + p, nB = w8 + p + 1;
      const int aA = off[nA], dA = deg[nA];
      const int aB = off[nB], dB = deg[nB];
      float4 accA = make_float4(0.f, 0.f, 0.f, 0.f);
      float4 accB = make_float4(0.f, 0.f, 0.f, 0.f);
      const int mx = dA > dB ? dA : dB;
      for (int eb = 0; eb < mx; eb += 8) {
        const int i = eb + es;
        if (i < dA) {
          float4 f = zl4[(size_t)lds_s[aA + i] * 8 + fi];
          accA.x += f.x; accA.y += f.y; accA.z += f.z; accA.w += f.w;
        }
        if (i < dB) {
          float4 f = zl4[(size_t)lds_s[aB + i] * 8 + fi];
          accB.x += f.x; accB.y += f.y; accB.z += f.z; accB.w += f.w;
        }
      }
#pragma unroll
      for (int m = 8; m < 64; m <<= 1) {
        accA.x += __shfl_xor(accA.x, m, 64);
        accA.y += __shfl_xor(accA.y, m, 64);
        accA.z += __shfl_xor(accA.z, m, 64);
        accA.w += __shfl_xor(accA.w, m, 64);
        accB.x += __shfl_xor(accB.x, m, 64);
        accB.y += __shfl_xor(accB.y, m, 64);
        accB.z += __shfl_xor(accB.z, m, 64);
        accB.w += __shfl_xor(accB.w, m, 64);
      }
      if (es == 0) {
        const float4 b4 = *(const float4*)(bsh + fi * 4);
        if (n0 + nA < N) {
          const float rdA = 1.0f / (float)(dA > 1 ? dA : 1);
          const float4 sA =
              *(const float4*)(zr + (size_t)(n0 + nA) * 32 + fi * 4);
          float4 h;
          h.x = fmaxf(accA.x * rdA + b4.x + sA.x, 0.f);
          h.y = fmaxf(accA.y * rdA + b4.y + sA.y, 0.f);
          h.z = fmaxf(accA.z * rdA + b4.z + sA.z, 0.f);
          h.w = fmaxf(accA.w * rdA + b4.w + sA.w, 0.f);
          *(float4*)(hbuf + nA * 36 + fi * 4) = h;
        }
        if (n0 + nB < N) {
          const float rdB = 1.0f / (float)(dB > 1 ? dB : 1);
          const float4 sB =
              *(const float4*)(zr + (size_t)(n0 + nB) * 32 + fi * 4);
          float4 h;
          h.x = fmaxf(accB.x * rdB + b4.x + sB.x, 0.f);
          h.y = fmaxf(accB.y * rdB + b4.y + sB.y, 0.f);
          h.z = fmaxf(accB.z * rdB + b4.z + sB.z, 0.f);
          h.w = fmaxf(accB.w * rdB + b4.w + sB.w, 0.f);
          *(float4*)(hbuf + nB * 36 + fi * 4) = h;
        }
      }
    }
    __syncthreads();

    // W2 mini-GEMM: 16 groups of 32 lanes, group g -> nodes g*4..g*4+3
    const int g = t >> 5, j = t & 31;
#pragma unroll
    for (int i = 0; i < 4; i++) {
      const int nl = g * 4 + i;
      const int node = n0 + nl;
      if (node >= N) break;
      const float h = hbuf[nl * 36 + j];
      float p0 = 0.f, p1 = 0.f;
#pragma unroll
      for (int jj = 0; jj < 32; jj++) {
        float hj = __shfl(h, jj, 32);
        p0 += hj * w2p[jj * 64 + j];
        p1 += hj * w2p[jj * 64 + 32 + j];
      }
      z2l[(size_t)node * 32 + j] = p0;
      z2r[(size_t)node * 32 + j] = p1;
    }
    __syncthreads();
  }
}

// ---- fused L2: sort + wide gather -> out (fully float4) ------------------
__global__ __launch_bounds__(512) void k_fagg2(
    const float* __restrict__ z2l, const float* __restrict__ z2r,
    const int* __restrict__ ebuf, const int* __restrict__ gcnt,
    const float* __restrict__ b2, float* __restrict__ out, int N, int rep_n) {
  __shared__ __align__(16) int lds_e[CAPE];
  __shared__ int lds_s[CAPE];
  __shared__ int deg[BKS];
  __shared__ int cur[BKS];
  __shared__ int off[BKS];
  __shared__ __align__(16) float bsh[32];
  const int t = threadIdx.x;
  const int k = blockIdx.x;
  int ne = gcnt[k * 32];
  if (ne > CAPE) ne = CAPE;
  const size_t base = (size_t)k * CAPE;

  for (int rep = 0; rep < rep_n; ++rep) {
    if (t < 32) bsh[t] = b2[t];

    SORT_PHASE(ebuf, ne)

    const float4* z24 = (const float4*)z2l;
    const int w = t >> 6, l = t & 63;
    const int es = l >> 3, fi = l & 7;
    const int n0 = k << 6;
    const int w8 = w * 8;
#pragma unroll
    for (int p = 0; p < 8; p += 2) {
      const int nA = w8 + p, nB = w8 + p + 1;
      const int aA = off[nA], dA = deg[nA];
      const int aB = off[nB], dB = deg[nB];
      float4 accA = make_float4(0.f, 0.f, 0.f, 0.f);
      float4 accB = make_float4(0.f, 0.f, 0.f, 0.f);
      const int mx = dA > dB ? dA : dB;
      for (int eb = 0; eb < mx; eb += 8) {
        const int i = eb + es;
        if (i < dA) {
          float4 f = z24[(size_t)lds_s[aA + i] * 8 + fi];
          accA.x += f.x; accA.y += f.y; accA.z += f.z; accA.w += f.w;
        }
        if (i < dB) {
          float4 f = z24[(size_t)lds_s[aB + i] * 8 + fi];
          accB.x += f.x; accB.y += f.y; accB.z += f.z; accB.w += f.w;
        }
      }
#pragma unroll
      for (int m = 8; m < 64; m <<= 1) {
        accA.x += __shfl_xor(accA.x, m, 64);
        accA.y += __shfl_xor(accA.y, m, 64);
        accA.z += __shfl_xor(accA.z, m, 64);
        accA.w += __shfl_xor(accA.w, m, 64);
        accB.x += __shfl_xor(accB.x, m, 64);
        accB.y += __shfl_xor(accB.y, m, 64);
        accB.z += __shfl_xor(accB.z, m, 64);
        accB.w += __shfl_xor(accB.w, m, 64);
      }
      if (es == 0) {
        const float4 b4 = *(const float4*)(bsh + fi * 4);
        if (n0 + nA < N) {
          const float rdA = 1.0f / (float)(dA > 1 ? dA : 1);
          const float4 sA =
              *(const float4*)(z2r + (size_t)(n0 + nA) * 32 + fi * 4);
          float4 o;
          o.x = accA.x * rdA + b4.x + sA.x;
          o.y = accA.y * rdA + b4.y + sA.y;
          o.z = accA.z * rdA + b4.z + sA.z;
          o.w = accA.w * rdA + b4.w + sA.w;
          *(float4*)(out + (size_t)(n0 + nA) * 32 + fi * 4) = o;
        }
        if (n0 + nB < N) {
          const float rdB = 1.0f / (float)(dB > 1 ? dB : 1);
          const float4 sB =
              *(const float4*)(z2r + (size_t)(n0 + nB) * 32 + fi * 4);
          float4 o;
          o.x = accB.x * rdB + b4.x + sB.x;
          o.y = accB.y * rdB + b4.y + sB.y;
          o.z = accB.z * rdB + b4.z + sB.z;
          o.w = accB.w * rdB + b4.w + sB.w;
          *(float4*)(out + (size_t)(n0 + nB) * 32 + fi * 4) = o;
        }
      }
    }
    __syncthreads();
  }
}

extern "C" void kernel_launch(void* const* d_in, const int* in_sizes, int n_in,
                              void* d_out, int out_size, void* d_ws,
                              size_t ws_size, hipStream_t stream) {
  const float* x = (const float*)d_in[0];
  const int* ei = (const int*)d_in[1];  // int32 (harness narrows int64)
  const float* W1l = (const float*)d_in[2];
  const float* b1 = (const float*)d_in[3];
  const float* W1r = (const float*)d_in[4];
  const float* W2l = (const float*)d_in[5];
  const float* b2 = (const float*)d_in[6];
  const float* W2r = (const float*)d_in[7];
  float* out = (float*)d_out;

  const int N = N_NODES;
  const int E = in_sizes[1] / 2;  // 800000

  float* zl = (float*)d_ws;                    // N*32
  float* zr = zl + (size_t)N * 32;             // N*32
  float* z2l = zr + (size_t)N * 32;            // N*32
  float* z2r = z2l + (size_t)N * 32;           // N*32
  int* ebuf = (int*)(z2r + (size_t)N * 32);    // REP*NB*CAPE
  int* gcnt = ebuf + (size_t)REP * NB * CAPE;  // REP*NB*32

  const int* srcp = ei;
  const int* dstp = ei + E;

  const int nblk_proj = (N + 63) / 64;  // 782

  int* ebuf_f = ebuf + (size_t)(REP - 1) * NB * CAPE;
  int* gcnt_f = gcnt + (size_t)(REP - 1) * NB * 32;

  hipMemsetAsync(gcnt, 0, (size_t)REP * NB * 32 * sizeof(int), stream);
  k_front<<<GB + nblk_proj, 256, 0, stream>>>(x, W1l, W1r, zl, zr, N, 128,
                                              srcp, dstp, gcnt, ebuf, E, REP);
  k_fagg1<<<NB, 512, 0, stream>>>(zl, zr, ebuf_f, gcnt_f, b1, W2l, W2r, z2l,
                                  z2r, N, REP);
  k_fagg2<<<NB, 512, 0, stream>>>(z2l, z2r, ebuf_f, gcnt_f, b2, out, N, REP);
}

// Round 8
// 161.721 us; speedup vs baseline: 4.6744x; 4.6744x over previous
//
#include <hip/hip_runtime.h>

// GraphSAGE 2-layer, N=50000, d=128->32->32, E=800000, fp32.
//
// R13: R12 instrumentation: fagg1 unit=66us (39% of total), VALUBusy 16%,
// occupancy 19%, HBM 5% -> LATENCY-bound gather: ~2 dependent chains/wave,
// MLP~12/CU vs ~500cy L3 latency. Fix:
//  (1) gather re-shape: wave = 8 groups x 8 lanes, group owns a node; one
//      coalesced 8-index load then __shfl(idx,q,8) broadcast -> 8
//      independent 128B row-gathers in flight per group (64/wave).
//  (2) sort dedup: fagg1 (which already builds lds_s) writes sorted adj
//      back to ebuf in-place + nod[node]=(off_abs,deg); fagg2 becomes a
//      lean LDS-free pure-gather kernel (1563 blocks x 256 thr).
// Pipeline: memset(gcnt) -> k_front(build+projL1) ->
//           k_fagg1(sort+gather+relu+W2 -> z2l/z2r, emits adj/nod) ->
//           k_fagg2(pure gather -> out).
// ws: zl|zr|z2l|z2r [N*32] | ebuf[NB*CAPE] | gcnt[NB*32] | nod[N int2]

#define N_NODES 50000
#define NB 782     // buckets = ceil(N/64)
#define BKS 64     // nodes per bucket
#define GB 256     // build blocks
#define CAPE 1280  // per-bucket capacity (mean 1023, sd 32; R8-verified)
#define TILE 3200  // build LDS staging tile (chunk=3128 fits in one)

// ---- k_front: build (blocks < GB) + L1 projection (blocks >= GB) ---------
__global__ __launch_bounds__(256) void k_front(
    const float* __restrict__ in, const float* __restrict__ Wl,
    const float* __restrict__ Wr, float* __restrict__ zl,
    float* __restrict__ zr, int N, int K, const int* __restrict__ src,
    const int* __restrict__ dst, int* __restrict__ gcnt,
    int* __restrict__ ebuf, int E) {
  __shared__ __align__(16) union {
    struct { float xs[64 * 68]; float ws[64 * 64]; } p;          // 33.8 KB
    struct { unsigned pe[TILE]; int hist[NB]; int cur[NB]; } b;  // 19.1 KB
  } sm;
  const int t = threadIdx.x;

  if (blockIdx.x < GB) {
    // ---------------- build role ----------------
    const int chunk = (((E + GB - 1) / GB) + 3) & ~3;  // 3128: 16B-aligned e0
    const int e0 = blockIdx.x * chunk;
    int e1 = e0 + chunk;
    if (e1 > E) e1 = E;
    for (int ts = e0; ts < e1; ts += TILE) {
      int te = ts + TILE;
      if (te > e1) te = e1;
      const int n = te - ts;
      if (n <= 0) break;
      for (int i = t; i < NB; i += 256) sm.b.hist[i] = 0;
      __syncthreads();
      {
        const int n4 = n >> 2;
        const int4* s4 = (const int4*)(src + ts);
        const int4* d4 = (const int4*)(dst + ts);
        for (int i = t; i < n4; i += 256) {
          int4 sv = s4[i];
          int4 dv = d4[i];
          int4 pk;
          pk.x = (sv.x << 16) | dv.x;
          pk.y = (sv.y << 16) | dv.y;
          pk.z = (sv.z << 16) | dv.z;
          pk.w = (sv.w << 16) | dv.w;
          *(int4*)(sm.b.pe + 4 * i) = pk;
          atomicAdd(&sm.b.hist[dv.x >> 6], 1);
          atomicAdd(&sm.b.hist[dv.y >> 6], 1);
          atomicAdd(&sm.b.hist[dv.z >> 6], 1);
          atomicAdd(&sm.b.hist[dv.w >> 6], 1);
        }
        for (int i = (n4 << 2) + t; i < n; i += 256) {
          unsigned s = (unsigned)src[ts + i];
          unsigned d = (unsigned)dst[ts + i];
          sm.b.pe[i] = (s << 16) | d;
          atomicAdd(&sm.b.hist[d >> 6], 1);
        }
      }
      __syncthreads();
      for (int c = t; c < NB; c += 256) {
        int h = sm.b.hist[c];
        sm.b.cur[c] = h ? atomicAdd(&gcnt[c * 32], h) : 0;  // padded line/bkt
      }
      __syncthreads();
      for (int i = t; i < n; i += 256) {
        unsigned pe = sm.b.pe[i];
        int d = (int)(pe & 0xFFFFu);
        int s = (int)(pe >> 16);
        int c = d >> 6;
        int p = atomicAdd(&sm.b.cur[c], 1);
        if (p < CAPE) ebuf[(size_t)c * CAPE + p] = (s << 6) | (d & 63);
      }
      __syncthreads();
    }
    return;
  }

  // ------- projection role: zl[n][0:32)=in@Wl, zr[n][0:32)=in@Wr ----------
  const int n0 = (blockIdx.x - GB) * 64;
  const int nvalid = (N - n0) < 64 ? (N - n0) : 64;
  const int tx = t & 15, ty = t >> 4;
  const int c0 = tx * 4;
  const int nl = ty * 4;

  float acc[4][4];
#pragma unroll
  for (int i = 0; i < 4; i++)
#pragma unroll
    for (int j = 0; j < 4; j++) acc[i][j] = 0.f;

  for (int kc = 0; kc < K; kc += 64) {
    const int KC = (K - kc) < 64 ? (K - kc) : 64;
    for (int i = t; i < KC * 32; i += 256) {
      int k = i >> 5, c = i & 31;
      sm.p.ws[k * 64 + c] = Wl[(size_t)(kc + k) * 32 + c];
      sm.p.ws[k * 64 + 32 + c] = Wr[(size_t)(kc + k) * 32 + c];
    }
    {
      const int kq = KC >> 2;
      const int sh = (KC == 64) ? 4 : 3;
      const int lim = nvalid * kq;
      for (int i = t; i < lim; i += 256) {
        int n = i >> sh, q = i & (kq - 1);
        float4 v = *(const float4*)(in + (size_t)(n0 + n) * K + kc + q * 4);
        *(float4*)(sm.p.xs + n * 68 + q * 4) = v;
      }
    }
    __syncthreads();

    const float* x0 = sm.p.xs + (nl + 0) * 68;
    const float* x1 = sm.p.xs + (nl + 1) * 68;
    const float* x2 = sm.p.xs + (nl + 2) * 68;
    const float* x3 = sm.p.xs + (nl + 3) * 68;
    for (int k = 0; k < KC; k += 4) {
      float4 xa = *(const float4*)(x0 + k);
      float4 xb = *(const float4*)(x1 + k);
      float4 xc = *(const float4*)(x2 + k);
      float4 xd = *(const float4*)(x3 + k);
#pragma unroll
      for (int kk = 0; kk < 4; kk++) {
        float4 w = *(const float4*)(sm.p.ws + (k + kk) * 64 + c0);
        float va = ((const float*)&xa)[kk];
        float vb = ((const float*)&xb)[kk];
        float vc = ((const float*)&xc)[kk];
        float vd = ((const float*)&xd)[kk];
        acc[0][0] += va * w.x; acc[0][1] += va * w.y;
        acc[0][2] += va * w.z; acc[0][3] += va * w.w;
        acc[1][0] += vb * w.x; acc[1][1] += vb * w.y;
        acc[1][2] += vb * w.z; acc[1][3] += vb * w.w;
        acc[2][0] += vc * w.x; acc[2][1] += vc * w.y;
        acc[2][2] += vc * w.z; acc[2][3] += vc * w.w;
        acc[3][0] += vd * w.x; acc[3][1] += vd * w.y;
        acc[3][2] += vd * w.z; acc[3][3] += vd * w.w;
      }
    }
    __syncthreads();
  }
#pragma unroll
  for (int i = 0; i < 4; i++) {
    int node = n0 + nl + i;
    if (node < N) {
      float4 v = make_float4(acc[i][0], acc[i][1], acc[i][2], acc[i][3]);
      if (c0 < 32)
        *(float4*)(zl + (size_t)node * 32 + c0) = v;
      else
        *(float4*)(zr + (size_t)node * 32 + (c0 - 32)) = v;
    }
  }
}

// ---- fused L1: sort + MLP-gather + relu + W2 proj; emits adj/nod ---------
// 512 thr: sort phase as R11; gather: group g=t>>3 (64 groups) owns node g,
// fi=t&7 covers the 8 float4 of a row. Per batch: one coalesced 8-index
// read + 8 shfl-broadcast row gathers (8 chains in flight per group).
__global__ __launch_bounds__(512) void k_fagg1(
    const float* __restrict__ zl, const float* __restrict__ zr,
    int* __restrict__ ebuf, const int* __restrict__ gcnt,
    const float* __restrict__ b1, const float* __restrict__ W2l,
    const float* __restrict__ W2r, float* __restrict__ z2l,
    float* __restrict__ z2r, int2* __restrict__ nod, int N) {
  __shared__ __align__(16) int lds_e[CAPE];
  __shared__ int lds_s[CAPE];
  __shared__ int deg[BKS];
  __shared__ int cur[BKS];
  __shared__ int off[BKS];
  __shared__ float w2p[32 * 64];  // [jj][0:32]=W2l[jj], [32:64]=W2r[jj]
  __shared__ __align__(16) float bsh[32];
  __shared__ __align__(16) float hbuf[BKS * 36];  // h, stride 36
  const int t = threadIdx.x;
  const int k = blockIdx.x;
  int ne = gcnt[k * 32];
  if (ne > CAPE) ne = CAPE;  // statistically never hit; memory-safety clamp
  const size_t base = (size_t)k * CAPE;

  for (int i = t; i < 2048; i += 512) {
    int jj = i >> 6, c = i & 63;
    w2p[i] = (c < 32) ? W2l[jj * 32 + c] : W2r[jj * 32 + (c - 32)];
  }
  if (t < 32) bsh[t] = b1[t];

  // ---- counting sort (int-only LDS atomics) ----
  {
    const int ne4 = ne >> 2;
    const int4* eb4 = (const int4*)(ebuf + base);
    for (int i = t; i < ne4; i += 512) *(int4*)(lds_e + 4 * i) = eb4[i];
    for (int i = (ne4 << 2) + t; i < ne; i += 512) lds_e[i] = ebuf[base + i];
  }
  if (t < BKS) deg[t] = 0;
  __syncthreads();
  for (int i = t; i < ne; i += 512) atomicAdd(&deg[lds_e[i] & 63], 1);
  __syncthreads();
  if (t < 64) {
    int d = deg[t];
    int x = d;
#pragma unroll
    for (int o = 1; o < 64; o <<= 1) {
      int y = __shfl_up(x, o, 64);
      if (t >= o) x += y;
    }
    off[t] = x - d;
    cur[t] = x - d;
  }
  __syncthreads();
  for (int i = t; i < ne; i += 512) {
    int v = lds_e[i];
    int p = atomicAdd(&cur[v & 63], 1);
    lds_s[p] = v >> 6;
  }
  __syncthreads();

  // ---- emit sorted adj (in-place) + nod for fagg2 ----
  for (int i = t; i < ne; i += 512) ebuf[base + i] = lds_s[i];
  if (t < BKS) {
    int node = (k << 6) + t;
    if (node < N) nod[node] = make_int2((int)base + off[t], deg[t]);
  }

  // ---- gather: 8 chains in flight per 8-lane group ----
  const int g = t >> 3, fi = t & 7;
  const int node = (k << 6) + g;
  const int a = off[g], dg = deg[g];
  const float4* zl4 = (const float4*)zl;  // row = 8 float4
  float4 acc = make_float4(0.f, 0.f, 0.f, 0.f);
  for (int b0 = 0; b0 < dg; b0 += 8) {
    const int myi = b0 + fi;
    int sidx = (myi < dg) ? lds_s[a + myi] : 0;
#pragma unroll
    for (int q = 0; q < 8; q++) {
      if (b0 + q < dg) {
        int s = __shfl(sidx, q, 8);
        float4 f = zl4[(size_t)s * 8 + fi];
        acc.x += f.x; acc.y += f.y; acc.z += f.z; acc.w += f.w;
      }
    }
  }
  if (node < N) {
    const float rd = 1.0f / (float)(dg > 1 ? dg : 1);
    const float4 b4 = *(const float4*)(bsh + fi * 4);
    const float4 sA = *(const float4*)(zr + (size_t)node * 32 + fi * 4);
    float4 h;
    h.x = fmaxf(acc.x * rd + b4.x + sA.x, 0.f);
    h.y = fmaxf(acc.y * rd + b4.y + sA.y, 0.f);
    h.z = fmaxf(acc.z * rd + b4.z + sA.z, 0.f);
    h.w = fmaxf(acc.w * rd + b4.w + sA.w, 0.f);
    *(float4*)(hbuf + g * 36 + fi * 4) = h;
  }
  __syncthreads();

  // ---- W2 mini-GEMM: 16 groups of 32 lanes, group gg -> nodes gg*4..+3 ---
  const int gg = t >> 5, j = t & 31;
  const int n0 = k << 6;
#pragma unroll
  for (int i = 0; i < 4; i++) {
    const int nl = gg * 4 + i;
    const int nodei = n0 + nl;
    if (nodei >= N) break;
    const float h = hbuf[nl * 36 + j];
    float p0 = 0.f, p1 = 0.f;
#pragma unroll
    for (int jj = 0; jj < 32; jj++) {
      float hj = __shfl(h, jj, 32);
      p0 += hj * w2p[jj * 64 + j];
      p1 += hj * w2p[jj * 64 + 32 + j];
    }
    z2l[(size_t)nodei * 32 + j] = p0;
    z2r[(size_t)nodei * 32 + j] = p1;
  }
}

// ---- fused L2: lean LDS-free gather -> out -------------------------------
// 256 thr = 32 groups of 8 lanes, one node each; grid ceil(N/32).
__global__ __launch_bounds__(256) void k_fagg2(
    const float* __restrict__ z2l, const float* __restrict__ z2r,
    const int* __restrict__ adj, const int2* __restrict__ nod,
    const float* __restrict__ b2, float* __restrict__ out, int N) {
  __shared__ __align__(16) float bsh[32];
  const int t = threadIdx.x;
  if (t < 32) bsh[t] = b2[t];
  __syncthreads();
  const int g = t >> 3, fi = t & 7;
  const int node = blockIdx.x * 32 + g;
  if (node >= N) return;
  const int2 nd = nod[node];
  const float4* z24 = (const float4*)z2l;
  float4 acc = make_float4(0.f, 0.f, 0.f, 0.f);
  for (int b0 = 0; b0 < nd.y; b0 += 8) {
    const int myi = b0 + fi;
    int sidx = (myi < nd.y) ? adj[nd.x + myi] : 0;
#pragma unroll
    for (int q = 0; q < 8; q++) {
      if (b0 + q < nd.y) {
        int s = __shfl(sidx, q, 8);
        float4 f = z24[(size_t)s * 8 + fi];
        acc.x += f.x; acc.y += f.y; acc.z += f.z; acc.w += f.w;
      }
    }
  }
  const float rd = 1.0f / (float)(nd.y > 1 ? nd.y : 1);
  const float4 b4 = *(const float4*)(bsh + fi * 4);
  const float4 sB = *(const float4*)(z2r + (size_t)node * 32 + fi * 4);
  float4 o;
  o.x = acc.x * rd + b4.x + sB.x;
  o.y = acc.y * rd + b4.y + sB.y;
  o.z = acc.z * rd + b4.z + sB.z;
  o.w = acc.w * rd + b4.w + sB.w;
  *(float4*)(out + (size_t)node * 32 + fi * 4) = o;
}

extern "C" void kernel_launch(void* const* d_in, const int* in_sizes, int n_in,
                              void* d_out, int out_size, void* d_ws,
                              size_t ws_size, hipStream_t stream) {
  const float* x = (const float*)d_in[0];
  const int* ei = (const int*)d_in[1];  // int32 (harness narrows int64)
  const float* W1l = (const float*)d_in[2];
  const float* b1 = (const float*)d_in[3];
  const float* W1r = (const float*)d_in[4];
  const float* W2l = (const float*)d_in[5];
  const float* b2 = (const float*)d_in[6];
  const float* W2r = (const float*)d_in[7];
  float* out = (float*)d_out;

  const int N = N_NODES;
  const int E = in_sizes[1] / 2;  // 800000

  float* zl = (float*)d_ws;                    // N*32
  float* zr = zl + (size_t)N * 32;             // N*32
  float* z2l = zr + (size_t)N * 32;            // N*32
  float* z2r = z2l + (size_t)N * 32;           // N*32
  int* ebuf = (int*)(z2r + (size_t)N * 32);    // NB*CAPE
  int* gcnt = ebuf + (size_t)NB * CAPE;        // NB*32 (one line per bucket)
  int2* nod = (int2*)(gcnt + (size_t)NB * 32); // N

  const int* srcp = ei;
  const int* dstp = ei + E;

  const int nblk_proj = (N + 63) / 64;   // 782
  const int nblk_f2 = (N + 31) / 32;     // 1563

  hipMemsetAsync(gcnt, 0, (size_t)NB * 32 * sizeof(int), stream);
  k_front<<<GB + nblk_proj, 256, 0, stream>>>(x, W1l, W1r, zl, zr, N, 128,
                                              srcp, dstp, gcnt, ebuf, E);
  k_fagg1<<<NB, 512, 0, stream>>>(zl, zr, ebuf, gcnt, b1, W2l, W2r, z2l, z2r,
                                  nod, N);
  k_fagg2<<<nblk_f2, 256, 0, stream>>>(z2l, z2r, ebuf, nod, b2, out, N);
}